// Round 3
// baseline (258.009 us; speedup 1.0000x reference)
//
#include <hip/hip_runtime.h>

#define NNODES 40960
#define NEDGES 81920
#define NG     1024
#define NCOMBO 512

// ---------- etab[c,j] = sum of 3 bond embeddings; also zeroes cnt ----------
__global__ void k_etab(const float* __restrict__ bemb, float* __restrict__ etab,
                       int* __restrict__ cnt) {
    int gid = blockIdx.x * blockDim.x + threadIdx.x;   // 512*16
    int c = gid >> 4, j = gid & 15;
    int f0 = c >> 6, f1 = (c >> 3) & 7, f2 = c & 7;
    etab[gid] = bemb[(0 * 8 + f0) * 16 + j] + bemb[(1 * 8 + f1) * 16 + j] +
                bemb[(2 * 8 + f2) * 16 + j];
    if ((gid & 15) == 0) cnt[c] = 0;
}

// ---------- cid per edge + histogram ----------
__global__ void k_hist(const int* __restrict__ ef, int* __restrict__ cid,
                       int* __restrict__ cnt) {
    int e = blockIdx.x * blockDim.x + threadIdx.x;
    if (e >= NEDGES) return;
    int c = (ef[e * 3] << 6) | (ef[e * 3 + 1] << 3) | ef[e * 3 + 2];
    cid[e] = c;
    atomicAdd(&cnt[c], 1);
}

// ---------- exclusive scan of 512 counts (1 block, 512 threads) ----------
__global__ void k_scan(const int* __restrict__ cnt, int* __restrict__ bstart,
                       int* __restrict__ bfill) {
    __shared__ int s[NCOMBO];
    int t = threadIdx.x;
    int my = cnt[t];
    s[t] = my;
    __syncthreads();
    for (int off = 1; off < NCOMBO; off <<= 1) {
        int v = (t >= off) ? s[t - off] : 0;
        __syncthreads();
        s[t] += v;
        __syncthreads();
    }
    int excl = s[t] - my;
    bstart[t] = excl;
    bfill[t] = excl;
    if (t == NCOMBO - 1) bstart[NCOMBO] = NEDGES;
}

// ---------- scatter edges into buckets ----------
__global__ void k_scatter(const int* __restrict__ cid, const int* __restrict__ src,
                          const int* __restrict__ dst, int* __restrict__ bfill,
                          int2* __restrict__ ebuf) {
    int e = blockIdx.x * blockDim.x + threadIdx.x;
    if (e >= NEDGES) return;
    int pos = atomicAdd(&bfill[cid[e]], 1);
    ebuf[pos] = make_int2(src[e], dst[e]);
}

// ---------- fused atom encoder + root transform ----------
// block = 256 = 4 nodes x 64 dims; phase2 split-k over 2 half-waves
__global__ __launch_bounds__(256) void k_node(
    const int* __restrict__ nf, const float* __restrict__ emb,
    const float* __restrict__ root, const float* __restrict__ bias,
    float* __restrict__ x, float* __restrict__ out) {
    __shared__ float xs[4][64];
    int t = threadIdx.x;
    int nn = t >> 6, d = t & 63;
    int n = blockIdx.x * 4 + nn;
    const int* nfr = nf + n * 9;
    float acc = 0.f;
#pragma unroll
    for (int c = 0; c < 9; ++c) {
        int idx = nfr[c];
        acc += emb[((c << 7) + idx) * 64 + d];
    }
    x[n * 64 + d] = acc;
    xs[nn][d] = acc;
    __syncthreads();
    int o = t & 31, h = (t >> 5) & 1;
    float s = h ? 0.f : bias[o];
    int k0 = h * 32;
#pragma unroll
    for (int kq = 0; kq < 8; ++kq) {
        float4 xv = *reinterpret_cast<const float4*>(&xs[nn][k0 + kq * 4]);
        s += xv.x * root[(k0 + kq * 4 + 0) * 32 + o];
        s += xv.y * root[(k0 + kq * 4 + 1) * 32 + o];
        s += xv.z * root[(k0 + kq * 4 + 2) * 32 + o];
        s += xv.w * root[(k0 + kq * 4 + 3) * 32 + o];
    }
    s += __shfl_xor(s, 32);
    if (!h) out[n * 32 + o] = s;
}

// ---------- naive GEMM (small K only) ----------
__global__ void k_gemm_naive(const float* __restrict__ A, const float* __restrict__ B,
                             const float* __restrict__ bias, float* __restrict__ C,
                             int M, int N, int K, int relu) {
    int gid = blockIdx.x * blockDim.x + threadIdx.x;
    if (gid >= M * N) return;
    int m = gid / N, n = gid - m * N;
    const float* a = A + m * K;
    float acc = bias ? bias[n] : 0.f;
    for (int k = 0; k < K; ++k) acc += a[k] * B[k * N + n];
    if (relu) acc = fmaxf(acc, 0.f);
    C[gid] = acc;
}

// ---------- tiled GEMM, 64x64 tile, 4x4 micro, split-K over z ----------
template <int BM, int BN, int BK, int TM, int TN>
__global__ __launch_bounds__(256)
void k_gemm_tiled(const float* __restrict__ A, const float* __restrict__ B,
                  const float* __restrict__ bias, float* __restrict__ C,
                  float* __restrict__ Cp, int M, int N, int K, int KS, int relu) {
    constexpr int TX = BN / TN;
    constexpr int TY = BM / TM;
    static_assert(TX * TY == 256, "block must be 256 threads");
    __shared__ float As[BK][BM + 4];
    __shared__ float Bs[BK][BN + 4];
    const int tx = threadIdx.x % TX, ty = threadIdx.x / TX;
    const int row0 = blockIdx.y * BM, col0 = blockIdx.x * BN;
    const int z = blockIdx.z;
    const int k_begin = z * KS, k_end = k_begin + KS;

    const int am = threadIdx.x >> 2;
    const int ak = (threadIdx.x & 3) << 2;
    const int bk = threadIdx.x >> 4;
    const int bn = (threadIdx.x & 15) << 2;

    float acc[TM][TN] = {};
    for (int k0 = k_begin; k0 < k_end; k0 += BK) {
        float4 av = *reinterpret_cast<const float4*>(&A[(row0 + am) * K + k0 + ak]);
        float4 bv = *reinterpret_cast<const float4*>(&B[(k0 + bk) * N + col0 + bn]);
        As[ak + 0][am] = av.x;
        As[ak + 1][am] = av.y;
        As[ak + 2][am] = av.z;
        As[ak + 3][am] = av.w;
        *reinterpret_cast<float4*>(&Bs[bk][bn]) = bv;
        __syncthreads();
#pragma unroll
        for (int k = 0; k < BK; ++k) {
            float a[TM], b[TN];
            *reinterpret_cast<float4*>(a) =
                *reinterpret_cast<const float4*>(&As[k][ty * TM]);
            *reinterpret_cast<float4*>(b) =
                *reinterpret_cast<const float4*>(&Bs[k][tx * TN]);
#pragma unroll
            for (int i = 0; i < TM; ++i)
#pragma unroll
                for (int j = 0; j < TN; ++j) acc[i][j] += a[i] * b[j];
        }
        __syncthreads();
    }

    const int MN = M * N;
    if (gridDim.z == 1) {
#pragma unroll
        for (int i = 0; i < TM; ++i) {
            int r = row0 + ty * TM + i;
            float4 v;
            v.x = acc[i][0]; v.y = acc[i][1]; v.z = acc[i][2]; v.w = acc[i][3];
            int c = col0 + tx * TN;
            if (bias) { v.x += bias[c]; v.y += bias[c+1]; v.z += bias[c+2]; v.w += bias[c+3]; }
            if (relu) { v.x = fmaxf(v.x,0.f); v.y = fmaxf(v.y,0.f);
                        v.z = fmaxf(v.z,0.f); v.w = fmaxf(v.w,0.f); }
            *reinterpret_cast<float4*>(&C[r * N + c]) = v;
        }
    } else {
        float* dstp = Cp + z * MN;
#pragma unroll
        for (int i = 0; i < TM; ++i) {
            int r = row0 + ty * TM + i;
            float4 v;
            v.x = acc[i][0]; v.y = acc[i][1]; v.z = acc[i][2]; v.w = acc[i][3];
            *reinterpret_cast<float4*>(&dstp[r * N + col0 + tx * TN]) = v;
        }
    }
}

// ---------- split-K reduce ----------
__global__ void k_reduceK(const float* __restrict__ Cp, const float* __restrict__ bias,
                          float* __restrict__ C, int MN, int N, int nz, int relu) {
    int i4 = (blockIdx.x * 256 + threadIdx.x) * 4;
    if (i4 >= MN) return;
    float4 acc = *reinterpret_cast<const float4*>(&Cp[i4]);
    for (int z = 1; z < nz; ++z) {
        float4 t = *reinterpret_cast<const float4*>(&Cp[z * MN + i4]);
        acc.x += t.x; acc.y += t.y; acc.z += t.z; acc.w += t.w;
    }
    if (bias) {
        int c = i4 % N;
        acc.x += bias[c]; acc.y += bias[c + 1]; acc.z += bias[c + 2]; acc.w += bias[c + 3];
    }
    if (relu) {
        acc.x = fmaxf(acc.x, 0.f); acc.y = fmaxf(acc.y, 0.f);
        acc.z = fmaxf(acc.z, 0.f); acc.w = fmaxf(acc.w, 0.f);
    }
    *reinterpret_cast<float4*>(&C[i4]) = acc;
}

// ---------- bucketed NNConv message + scatter: W[:,o] in registers ----------
// grid = (3, NCOMBO); block 256 = 8 edge-slots x 32 o
__global__ __launch_bounds__(256) void k_msg2(
    const float* __restrict__ x, const float* __restrict__ wtab,
    const int* __restrict__ bstart, const int2* __restrict__ ebuf,
    float* __restrict__ out) {
    __shared__ float xs[64][64];
    __shared__ int2 es[64];
    const int t = threadIdx.x;
    const int c = blockIdx.y;
    const int beg = bstart[c], cnt = bstart[c + 1] - beg;
    if (cnt == 0) return;
    const int o = t & 31;
    float W[64];
    const float* wp = wtab + (c << 11) + o;
#pragma unroll
    for (int k = 0; k < 64; ++k) W[k] = wp[k << 5];

    for (int chunk = blockIdx.x * 64; chunk < cnt; chunk += gridDim.x * 64) {
        int nE = min(64, cnt - chunk);
        if (t < nE) es[t] = ebuf[beg + chunk + t];
        __syncthreads();
        for (int i = t; i < nE * 64; i += 256) {
            int r = i >> 6, d = i & 63;
            xs[r][d] = x[es[r].x * 64 + d];
        }
        __syncthreads();
        for (int e = t >> 5; e < nE; e += 8) {
            float acc = 0.f;
#pragma unroll
            for (int kq = 0; kq < 16; ++kq) {
                float4 xv = *reinterpret_cast<const float4*>(&xs[e][kq * 4]);
                acc += xv.x * W[kq * 4 + 0] + xv.y * W[kq * 4 + 1] +
                       xv.z * W[kq * 4 + 2] + xv.w * W[kq * 4 + 3];
            }
            atomicAdd(&out[es[e].y * 32 + o], acc);
        }
        __syncthreads();
    }
}

// ---------- fused readout tail ----------
__global__ __launch_bounds__(256) void k_tail(
    const float* __restrict__ f2,
    const float* __restrict__ mW3, const float* __restrict__ mb3,
    const float* __restrict__ mW4, const float* __restrict__ mb4,
    const float* __restrict__ mW5, const float* __restrict__ mb5,
    float* __restrict__ outv) {
    __shared__ float s2[4][128];
    __shared__ float s3[4][32];
    __shared__ float s4[4][8];
    const int w = threadIdx.x >> 6, lane = threadIdx.x & 63;
    const int g = blockIdx.x * 4 + w;
    s2[w][lane] = f2[g * 128 + lane];
    s2[w][64 + lane] = f2[g * 128 + 64 + lane];
    __syncthreads();
    if (lane < 32) {
        float acc = mb3[lane];
#pragma unroll 8
        for (int k = 0; k < 128; ++k) acc += s2[w][k] * mW3[k * 32 + lane];
        s3[w][lane] = fmaxf(acc, 0.f);
    }
    __syncthreads();
    if (lane < 8) {
        float acc = mb4[lane];
#pragma unroll
        for (int k = 0; k < 32; ++k) acc += s3[w][k] * mW4[k * 8 + lane];
        s4[w][lane] = fmaxf(acc, 0.f);
    }
    __syncthreads();
    if (lane == 0) {
        float acc = mb5[0];
#pragma unroll
        for (int k = 0; k < 8; ++k) acc += s4[w][k] * mW5[k];
        outv[g] = acc;
    }
}

extern "C" void kernel_launch(void* const* d_in, const int* in_sizes, int n_in,
                              void* d_out, int out_size, void* d_ws, size_t ws_size,
                              hipStream_t stream) {
    const int*   nf      = (const int*)d_in[0];
    const int*   ef      = (const int*)d_in[1];
    const int*   eidx    = (const int*)d_in[2];
    const float* atom_emb= (const float*)d_in[4];
    const float* bond_emb= (const float*)d_in[5];
    const float* gW1     = (const float*)d_in[6];
    const float* gW2     = (const float*)d_in[7];
    const float* gW3     = (const float*)d_in[8];
    const float* root    = (const float*)d_in[9];
    const float* cbias   = (const float*)d_in[10];
    const float* mW1     = (const float*)d_in[11];
    const float* mb1     = (const float*)d_in[12];
    const float* mW2     = (const float*)d_in[13];
    const float* mb2     = (const float*)d_in[14];
    const float* mW3     = (const float*)d_in[15];
    const float* mb3     = (const float*)d_in[16];
    const float* mW4     = (const float*)d_in[17];
    const float* mb4     = (const float*)d_in[18];
    const float* mW5     = (const float*)d_in[19];
    const float* mb5     = (const float*)d_in[20];

    const int* src = eidx;
    const int* dst = eidx + NEDGES;

    float* ws = (float*)d_ws;
    float* x    = ws;                       // 40960*64   = 2621440
    float* out  = x + 2621440;              // 40960*32   = 1310720
    float* etab = out + 1310720;            // 512*16     = 8192
    float* h1   = etab + 8192;              // 512*1024   = 524288
    float* h2   = h1 + 524288;              // 512*256    = 131072
    float* wtab = h2 + 131072;              // 512*2048   = 1048576
    float* f1   = wtab + 1048576;           // 1024*256   = 262144
    float* f2   = f1 + 262144;              // 1024*128   = 131072
    float* part = f2 + 131072;              // 2097152 (8 MB split-K partials)
    int*   cnt    = (int*)(part + 2097152); // 512
    int*   bstart = cnt + 512;              // 513
    int*   bfill  = bstart + 513;           // 512
    int*   cid    = bfill + 512;            // 81920
    // ebuf aliases f1: dead before f1 is written (k_msg2 precedes mW1 reduce)
    int2*  ebuf   = (int2*)f1;              // 81920 int2 = 163840 ints <= 262144 ok

    // 1. edge tables + bucketing
    k_etab<<<NCOMBO * 16 / 256, 256, 0, stream>>>(bond_emb, etab, cnt);
    k_hist<<<NEDGES / 256, 256, 0, stream>>>(ef, cid, cnt);
    k_scan<<<1, NCOMBO, 0, stream>>>(cnt, bstart, bfill);
    k_scatter<<<NEDGES / 256, 256, 0, stream>>>(cid, src, dst, bfill, ebuf);
    // 2. fused atom encoder + root transform
    k_node<<<NNODES / 4, 256, 0, stream>>>(nf, atom_emb, root, cbias, x, out);
    // 3. edge MLP on 512 unique combos
    k_gemm_naive<<<NCOMBO * 1024 / 256, 256, 0, stream>>>(etab, gW1, nullptr, h1,
                                                          NCOMBO, 1024, 16, 1);
    k_gemm_tiled<64, 64, 16, 4, 4><<<dim3(4, 8, 16), 256, 0, stream>>>(
        h1, gW2, nullptr, nullptr, part, NCOMBO, 256, 1024, 64, 0);
    k_reduceK<<<131072 / 1024, 256, 0, stream>>>(part, nullptr, h2, 131072, 256, 16, 1);
    k_gemm_tiled<64, 64, 16, 4, 4><<<dim3(32, 8, 2), 256, 0, stream>>>(
        h2, gW3, nullptr, nullptr, part, NCOMBO, 2048, 256, 128, 0);
    k_reduceK<<<1048576 / 1024, 256, 0, stream>>>(part, nullptr, wtab, 1048576, 2048, 2, 0);
    // 4. bucketed per-edge message + scatter-add
    k_msg2<<<dim3(3, NCOMBO), 256, 0, stream>>>(x, wtab, bstart, ebuf, out);
    // 5. readout
    k_gemm_tiled<64, 64, 16, 4, 4><<<dim3(4, 16, 8), 256, 0, stream>>>(
        out, mW1, nullptr, nullptr, part, NG, 256, 1280, 160, 0);
    k_reduceK<<<262144 / 1024, 256, 0, stream>>>(part, mb1, f1, 262144, 256, 8, 1);
    k_gemm_tiled<64, 64, 16, 4, 4><<<dim3(2, 16, 4), 256, 0, stream>>>(
        f1, mW2, nullptr, nullptr, part, NG, 128, 256, 64, 0);
    k_reduceK<<<131072 / 1024, 256, 0, stream>>>(part, mb2, f2, 131072, 128, 4, 1);
    // 6. fused tail
    k_tail<<<NG / 4, 256, 0, stream>>>(f2, mW3, mb3, mW4, mb4, mW5, mb5, (float*)d_out);
}

// Round 4
// 250.651 us; speedup vs baseline: 1.0294x; 1.0294x over previous
//
#include <hip/hip_runtime.h>

#define NNODES 40960
#define NEDGES 81920
#define NG     1024
#define NCOMBO 512

// ---------- etab[c,j] = sum of 3 bond embeddings; also zeroes cnt ----------
__global__ void k_etab(const float* __restrict__ bemb, float* __restrict__ etab,
                       int* __restrict__ cnt) {
    int gid = blockIdx.x * blockDim.x + threadIdx.x;   // 512*16
    int c = gid >> 4, j = gid & 15;
    int f0 = c >> 6, f1 = (c >> 3) & 7, f2 = c & 7;
    etab[gid] = bemb[(0 * 8 + f0) * 16 + j] + bemb[(1 * 8 + f1) * 16 + j] +
                bemb[(2 * 8 + f2) * 16 + j];
    if ((gid & 15) == 0) cnt[c] = 0;
}

// ---------- cid per edge + histogram ----------
__global__ void k_hist(const int* __restrict__ ef, int* __restrict__ cid,
                       int* __restrict__ cnt) {
    int e = blockIdx.x * blockDim.x + threadIdx.x;
    if (e >= NEDGES) return;
    int c = (ef[e * 3] << 6) | (ef[e * 3 + 1] << 3) | ef[e * 3 + 2];
    cid[e] = c;
    atomicAdd(&cnt[c], 1);
}

// ---------- exclusive scan of 512 counts (1 block) ----------
__global__ void k_scan(const int* __restrict__ cnt, int* __restrict__ bstart,
                       int* __restrict__ bfill) {
    __shared__ int s[NCOMBO];
    int t = threadIdx.x;
    int my = cnt[t];
    s[t] = my;
    __syncthreads();
    for (int off = 1; off < NCOMBO; off <<= 1) {
        int v = (t >= off) ? s[t - off] : 0;
        __syncthreads();
        s[t] += v;
        __syncthreads();
    }
    int excl = s[t] - my;
    bstart[t] = excl;
    bfill[t] = excl;
    if (t == NCOMBO - 1) bstart[NCOMBO] = NEDGES;
}

// ---------- scatter edges into buckets ----------
__global__ void k_scatter(const int* __restrict__ cid, const int* __restrict__ src,
                          const int* __restrict__ dst, int* __restrict__ bfill,
                          int2* __restrict__ ebuf) {
    int e = blockIdx.x * blockDim.x + threadIdx.x;
    if (e >= NEDGES) return;
    int pos = atomicAdd(&bfill[cid[e]], 1);
    ebuf[pos] = make_int2(src[e], dst[e]);
}

// ---------- fused atom encoder + root transform ----------
__global__ __launch_bounds__(256) void k_node(
    const int* __restrict__ nf, const float* __restrict__ emb,
    const float* __restrict__ root, const float* __restrict__ bias,
    float* __restrict__ x, float* __restrict__ out) {
    __shared__ float xs[4][64];
    int t = threadIdx.x;
    int nn = t >> 6, d = t & 63;
    int n = blockIdx.x * 4 + nn;
    const int* nfr = nf + n * 9;
    float acc = 0.f;
#pragma unroll
    for (int c = 0; c < 9; ++c) {
        int idx = nfr[c];
        acc += emb[((c << 7) + idx) * 64 + d];
    }
    x[n * 64 + d] = acc;
    xs[nn][d] = acc;
    __syncthreads();
    int o = t & 31, h = (t >> 5) & 1;
    float s = h ? 0.f : bias[o];
    int k0 = h * 32;
#pragma unroll
    for (int kq = 0; kq < 8; ++kq) {
        float4 xv = *reinterpret_cast<const float4*>(&xs[nn][k0 + kq * 4]);
        s += xv.x * root[(k0 + kq * 4 + 0) * 32 + o];
        s += xv.y * root[(k0 + kq * 4 + 1) * 32 + o];
        s += xv.z * root[(k0 + kq * 4 + 2) * 32 + o];
        s += xv.w * root[(k0 + kq * 4 + 3) * 32 + o];
    }
    s += __shfl_xor(s, 32);
    if (!h) out[n * 32 + o] = s;
}

// ---------- naive GEMM (small K only) ----------
__global__ void k_gemm_naive(const float* __restrict__ A, const float* __restrict__ B,
                             const float* __restrict__ bias, float* __restrict__ C,
                             int M, int N, int K, int relu) {
    int gid = blockIdx.x * blockDim.x + threadIdx.x;
    if (gid >= M * N) return;
    int m = gid / N, n = gid - m * N;
    const float* a = A + m * K;
    float acc = bias ? bias[n] : 0.f;
    for (int k = 0; k < K; ++k) acc += a[k] * B[k * N + n];
    if (relu) acc = fmaxf(acc, 0.f);
    C[gid] = acc;
}

// ---------- tiled GEMM, 64x64 tile, 4x4 micro, split-K over z ----------
template <int BM, int BN, int BK, int TM, int TN>
__global__ __launch_bounds__(256)
void k_gemm_tiled(const float* __restrict__ A, const float* __restrict__ B,
                  const float* __restrict__ bias, float* __restrict__ C,
                  float* __restrict__ Cp, int M, int N, int K, int KS, int relu) {
    constexpr int TX = BN / TN;
    constexpr int TY = BM / TM;
    static_assert(TX * TY == 256, "block must be 256 threads");
    __shared__ float As[BK][BM + 4];
    __shared__ float Bs[BK][BN + 4];
    const int tx = threadIdx.x % TX, ty = threadIdx.x / TX;
    const int row0 = blockIdx.y * BM, col0 = blockIdx.x * BN;
    const int z = blockIdx.z;
    const int k_begin = z * KS, k_end = k_begin + KS;

    const int am = threadIdx.x >> 2;
    const int ak = (threadIdx.x & 3) << 2;
    const int bk = threadIdx.x >> 4;
    const int bn = (threadIdx.x & 15) << 2;

    float acc[TM][TN] = {};
    for (int k0 = k_begin; k0 < k_end; k0 += BK) {
        float4 av = *reinterpret_cast<const float4*>(&A[(row0 + am) * K + k0 + ak]);
        float4 bv = *reinterpret_cast<const float4*>(&B[(k0 + bk) * N + col0 + bn]);
        As[ak + 0][am] = av.x;
        As[ak + 1][am] = av.y;
        As[ak + 2][am] = av.z;
        As[ak + 3][am] = av.w;
        *reinterpret_cast<float4*>(&Bs[bk][bn]) = bv;
        __syncthreads();
#pragma unroll
        for (int k = 0; k < BK; ++k) {
            float a[TM], b[TN];
            *reinterpret_cast<float4*>(a) =
                *reinterpret_cast<const float4*>(&As[k][ty * TM]);
            *reinterpret_cast<float4*>(b) =
                *reinterpret_cast<const float4*>(&Bs[k][tx * TN]);
#pragma unroll
            for (int i = 0; i < TM; ++i)
#pragma unroll
                for (int j = 0; j < TN; ++j) acc[i][j] += a[i] * b[j];
        }
        __syncthreads();
    }

    const int MN = M * N;
    if (gridDim.z == 1) {
#pragma unroll
        for (int i = 0; i < TM; ++i) {
            int r = row0 + ty * TM + i;
            float4 v;
            v.x = acc[i][0]; v.y = acc[i][1]; v.z = acc[i][2]; v.w = acc[i][3];
            int c = col0 + tx * TN;
            if (bias) { v.x += bias[c]; v.y += bias[c+1]; v.z += bias[c+2]; v.w += bias[c+3]; }
            if (relu) { v.x = fmaxf(v.x,0.f); v.y = fmaxf(v.y,0.f);
                        v.z = fmaxf(v.z,0.f); v.w = fmaxf(v.w,0.f); }
            *reinterpret_cast<float4*>(&C[r * N + c]) = v;
        }
    } else {
        float* dstp = Cp + z * MN;
#pragma unroll
        for (int i = 0; i < TM; ++i) {
            int r = row0 + ty * TM + i;
            float4 v;
            v.x = acc[i][0]; v.y = acc[i][1]; v.z = acc[i][2]; v.w = acc[i][3];
            *reinterpret_cast<float4*>(&dstp[r * N + col0 + tx * TN]) = v;
        }
    }
}

// ---------- split-K reduce ----------
__global__ void k_reduceK(const float* __restrict__ Cp, const float* __restrict__ bias,
                          float* __restrict__ C, int MN, int N, int nz, int relu) {
    int i4 = (blockIdx.x * 256 + threadIdx.x) * 4;
    if (i4 >= MN) return;
    float4 acc = *reinterpret_cast<const float4*>(&Cp[i4]);
    for (int z = 1; z < nz; ++z) {
        float4 t = *reinterpret_cast<const float4*>(&Cp[z * MN + i4]);
        acc.x += t.x; acc.y += t.y; acc.z += t.z; acc.w += t.w;
    }
    if (bias) {
        int c = i4 % N;
        acc.x += bias[c]; acc.y += bias[c + 1]; acc.z += bias[c + 2]; acc.w += bias[c + 3];
    }
    if (relu) {
        acc.x = fmaxf(acc.x, 0.f); acc.y = fmaxf(acc.y, 0.f);
        acc.z = fmaxf(acc.z, 0.f); acc.w = fmaxf(acc.w, 0.f);
    }
    *reinterpret_cast<float4*>(&C[i4]) = acc;
}

// ---------- bucketed NNConv msg; folds wtab 2-way split-K reduce into W load ----
// grid = (3, NCOMBO); block 256 = 8 half-waves x 32 o
__global__ __launch_bounds__(256) void k_msg2(
    const float* __restrict__ wpart, int MN,
    const float* __restrict__ x,
    const int* __restrict__ bstart, const int2* __restrict__ ebuf,
    float* __restrict__ out) {
    __shared__ float Ws[2048];
    __shared__ float xs[64][64];
    __shared__ int2 es[64];
    const int t = threadIdx.x;
    const int c = blockIdx.y;
    const int beg = bstart[c], cnt = bstart[c + 1] - beg;
    if (cnt == 0) return;
    // stage W = part0 + part1 (coalesced, once per block)
    const float* p0 = wpart + (c << 11);
    const float* p1 = p0 + MN;
#pragma unroll
    for (int i = 0; i < 8; ++i) {
        int idx = i * 256 + t;
        Ws[idx] = p0[idx] + p1[idx];
    }
    __syncthreads();
    const int o = t & 31;
    float W[64];
#pragma unroll
    for (int k = 0; k < 64; ++k) W[k] = Ws[(k << 5) | o];   // 2-way alias: free

    for (int chunk = blockIdx.x * 64; chunk < cnt; chunk += gridDim.x * 64) {
        int nE = min(64, cnt - chunk);
        if (t < nE) es[t] = ebuf[beg + chunk + t];
        __syncthreads();
        for (int i = t; i < nE * 16; i += 256) {
            int r = i >> 4, q = i & 15;
            reinterpret_cast<float4*>(xs[r])[q] =
                reinterpret_cast<const float4*>(x + es[r].x * 64)[q];
        }
        __syncthreads();
        for (int e = t >> 5; e < nE; e += 8) {
            float acc = 0.f;
#pragma unroll
            for (int kq = 0; kq < 16; ++kq) {
                float4 xv = *reinterpret_cast<const float4*>(&xs[e][kq * 4]);
                acc += xv.x * W[kq * 4 + 0] + xv.y * W[kq * 4 + 1] +
                       xv.z * W[kq * 4 + 2] + xv.w * W[kq * 4 + 3];
            }
            atomicAdd(&out[es[e].y * 32 + o], acc);
        }
        __syncthreads();
    }
}

// ---------- fused readout: mW1-partials reduce + mW2..mW5 chain ----------
// one block per 2 graphs; threads 0-127 -> graph g0, 128-255 -> g1
__global__ __launch_bounds__(256) void k_readout(
    const float* __restrict__ part, const float* __restrict__ mb1,
    const float* __restrict__ mW2, const float* __restrict__ mb2,
    const float* __restrict__ mW3, const float* __restrict__ mb3,
    const float* __restrict__ mW4, const float* __restrict__ mb4,
    const float* __restrict__ mW5, const float* __restrict__ mb5,
    float* __restrict__ outv) {
    __shared__ float f1s[2][256];
    __shared__ float f2s[2][128];
    __shared__ float f3s[2][32];
    __shared__ float f4s[2][8];
    const int t = threadIdx.x;
    const int gg = t >> 7, j = t & 127;
    const int g = blockIdx.x * 2 + gg;
    // f1 = relu(sum_z part[z] + mb1)
    for (int k = j; k < 256; k += 128) {
        float acc = mb1[k];
#pragma unroll
        for (int z = 0; z < 8; ++z) acc += part[z * (NG * 256) + g * 256 + k];
        f1s[gg][k] = fmaxf(acc, 0.f);
    }
    __syncthreads();
    // f2 = relu(f1 @ mW2 + mb2)
    {
        float acc = mb2[j];
#pragma unroll 8
        for (int k = 0; k < 256; ++k) acc += f1s[gg][k] * mW2[k * 128 + j];
        f2s[gg][j] = fmaxf(acc, 0.f);
    }
    __syncthreads();
    if (j < 32) {
        float acc = mb3[j];
#pragma unroll 8
        for (int k = 0; k < 128; ++k) acc += f2s[gg][k] * mW3[k * 32 + j];
        f3s[gg][j] = fmaxf(acc, 0.f);
    }
    __syncthreads();
    if (j < 8) {
        float acc = mb4[j];
#pragma unroll
        for (int k = 0; k < 32; ++k) acc += f3s[gg][k] * mW4[k * 8 + j];
        f4s[gg][j] = fmaxf(acc, 0.f);
    }
    __syncthreads();
    if (j == 0) {
        float acc = mb5[0];
#pragma unroll
        for (int k = 0; k < 8; ++k) acc += f4s[gg][k] * mW5[k];
        outv[g] = acc;
    }
}

extern "C" void kernel_launch(void* const* d_in, const int* in_sizes, int n_in,
                              void* d_out, int out_size, void* d_ws, size_t ws_size,
                              hipStream_t stream) {
    const int*   nf      = (const int*)d_in[0];
    const int*   ef      = (const int*)d_in[1];
    const int*   eidx    = (const int*)d_in[2];
    const float* atom_emb= (const float*)d_in[4];
    const float* bond_emb= (const float*)d_in[5];
    const float* gW1     = (const float*)d_in[6];
    const float* gW2     = (const float*)d_in[7];
    const float* gW3     = (const float*)d_in[8];
    const float* root    = (const float*)d_in[9];
    const float* cbias   = (const float*)d_in[10];
    const float* mW1     = (const float*)d_in[11];
    const float* mb1     = (const float*)d_in[12];
    const float* mW2     = (const float*)d_in[13];
    const float* mb2     = (const float*)d_in[14];
    const float* mW3     = (const float*)d_in[15];
    const float* mb3     = (const float*)d_in[16];
    const float* mW4     = (const float*)d_in[17];
    const float* mb4     = (const float*)d_in[18];
    const float* mW5     = (const float*)d_in[19];
    const float* mb5     = (const float*)d_in[20];

    const int* src = eidx;
    const int* dst = eidx + NEDGES;

    float* ws = (float*)d_ws;
    float* x    = ws;                       // 40960*64
    float* out  = x + 2621440;              // 40960*32
    float* etab = out + 1310720;            // 512*16
    float* h1   = etab + 8192;              // 512*1024
    float* h2   = h1 + 524288;              // 512*256
    float* dead = h2 + 131072;              // (ex-wtab, now ebuf home)
    float* part = dead + 1048576 + 262144 + 131072;  // 2097152 floats (8 MB)
    int*   cnt    = (int*)(part + 2097152);
    int*   bstart = cnt + 512;
    int*   bfill  = bstart + 513;
    int*   cid    = bfill + 512;
    int2*  ebuf   = (int2*)dead;            // 81920 int2 = 640 KB, fits

    // 1. edge tables + bucketing
    k_etab<<<NCOMBO * 16 / 256, 256, 0, stream>>>(bond_emb, etab, cnt);
    k_hist<<<NEDGES / 256, 256, 0, stream>>>(ef, cid, cnt);
    k_scan<<<1, NCOMBO, 0, stream>>>(cnt, bstart, bfill);
    k_scatter<<<NEDGES / 256, 256, 0, stream>>>(cid, src, dst, bfill, ebuf);
    // 2. fused atom encoder + root transform
    k_node<<<NNODES / 4, 256, 0, stream>>>(nf, atom_emb, root, cbias, x, out);
    // 3. edge MLP on 512 unique combos
    k_gemm_naive<<<NCOMBO * 1024 / 256, 256, 0, stream>>>(etab, gW1, nullptr, h1,
                                                          NCOMBO, 1024, 16, 1);
    k_gemm_tiled<64, 64, 16, 4, 4><<<dim3(4, 8, 16), 256, 0, stream>>>(
        h1, gW2, nullptr, nullptr, part, NCOMBO, 256, 1024, 64, 0);
    k_reduceK<<<131072 / 1024, 256, 0, stream>>>(part, nullptr, h2, 131072, 256, 16, 1);
    k_gemm_tiled<64, 64, 16, 4, 4><<<dim3(32, 8, 2), 256, 0, stream>>>(
        h2, gW3, nullptr, nullptr, part, NCOMBO, 2048, 256, 128, 0);
    // 4. bucketed msg (reads wtab partials directly, folds the 2-way reduce)
    k_msg2<<<dim3(3, NCOMBO), 256, 0, stream>>>(part, NCOMBO * 2048, x, bstart, ebuf, out);
    // 5. readout: mW1 split-K partials, then fused reduce+mW2..mW5
    k_gemm_tiled<64, 64, 16, 4, 4><<<dim3(4, 16, 8), 256, 0, stream>>>(
        out, mW1, nullptr, nullptr, part, NG, 256, 1280, 160, 0);
    k_readout<<<NG / 2, 256, 0, stream>>>(part, mb1, mW2, mb2, mW3, mb3,
                                          mW4, mb4, mW5, mb5, (float*)d_out);
}